// Round 3
// baseline (463.365 us; speedup 1.0000x reference)
//
#include <hip/hip_runtime.h>

#define NNODES 50000
#define NEDGES 500000
#define DIN 128
#define DHID 256
#define MPAD 50048   // 782 blocks * 64 rows
#define NI4 12500
#define NSB 49

typedef unsigned short u16;
typedef __attribute__((ext_vector_type(8))) _Float16 half8;
typedef __attribute__((ext_vector_type(4))) float f32x4;

__device__ __forceinline__ u16 f2h(float f) {
  union { _Float16 h; u16 u; } v; v.h = (_Float16)f; return v.u;
}
__device__ __forceinline__ float h2f(unsigned int u) {
  union { _Float16 h; u16 u; } v; v.u = (u16)u; return (float)v.h;
}

#define GLDS16(g, l) __builtin_amdgcn_global_load_lds( \
    (const __attribute__((address_space(1))) void*)(g), \
    (__attribute__((address_space(3))) void*)(l), 16, 0, 0)

__global__ void k_zero_i32(int* __restrict__ p, int n) {
  int i = blockIdx.x * blockDim.x + threadIdx.x;
  if (i < n) p[i] = 0;
}

__global__ void k_hist(const int* __restrict__ dst, int* __restrict__ deg, int e) {
  int i = blockIdx.x * blockDim.x + threadIdx.x;
  if (i < e) atomicAdd(&deg[dst[i]], 1);
}

__global__ __launch_bounds__(256) void k_blocksum(const int* __restrict__ deg,
                                                  int* __restrict__ partials) {
  __shared__ int red[256];
  int tid = threadIdx.x;
  int t4 = blockIdx.x * 256 + tid;
  int sum = 0;
  if (t4 < NI4) {
    int4 v = ((const int4*)deg)[t4];
    sum = v.x + v.y + v.z + v.w;
  }
  red[tid] = sum;
  __syncthreads();
  for (int off = 128; off > 0; off >>= 1) {
    if (tid < off) red[tid] += red[tid + off];
    __syncthreads();
  }
  if (tid == 0) partials[blockIdx.x] = red[0];
}

// exclusive scan -> row_ptr; fused: dinv = rsqrt(deg+1), zero deg (cursor reuse)
__global__ __launch_bounds__(256) void k_scan2(int* __restrict__ deg,
                                               const int* __restrict__ partials,
                                               int* __restrict__ row_ptr,
                                               float* __restrict__ dinv) {
  __shared__ int sdata[256];
  __shared__ int sprefix;
  int tid = threadIdx.x, bid = blockIdx.x;
  int t4 = bid * 256 + tid;
  int4 v = make_int4(0, 0, 0, 0);
  if (t4 < NI4) v = ((const int4*)deg)[t4];
  int tsum = v.x + v.y + v.z + v.w;
  sdata[tid] = tsum;
  if (tid == 0) {
    int pre = 0;
    for (int b = 0; b < bid; ++b) pre += partials[b];
    sprefix = pre;
  }
  __syncthreads();
  for (int off = 1; off < 256; off <<= 1) {
    int val = (tid >= off) ? sdata[tid - off] : 0;
    __syncthreads();
    sdata[tid] += val;
    __syncthreads();
  }
  if (t4 < NI4) {
    int run = sdata[tid] - tsum + sprefix;
    int base = t4 * 4;
    float4 dv;
    dv.x = rsqrtf((float)v.x + 1.0f);
    dv.y = rsqrtf((float)v.y + 1.0f);
    dv.z = rsqrtf((float)v.z + 1.0f);
    dv.w = rsqrtf((float)v.w + 1.0f);
    *(float4*)(dinv + base) = dv;
    row_ptr[base + 0] = run; run += v.x;
    row_ptr[base + 1] = run; run += v.y;
    row_ptr[base + 2] = run; run += v.z;
    row_ptr[base + 3] = run; run += v.w;
    if (base + 4 == NNODES) row_ptr[NNODES] = run;
    ((int4*)deg)[t4] = make_int4(0, 0, 0, 0);
  }
}

// CSR fill: packed 8-byte (src, nrm) entries
__global__ void k_fill(const int* __restrict__ src, const int* __restrict__ dst,
                       const float* __restrict__ dinv, const int* __restrict__ row_ptr,
                       int* __restrict__ cursor, long long* __restrict__ csr_pk, int e) {
  int i = blockIdx.x * blockDim.x + threadIdx.x;
  if (i < e) {
    int d = dst[i], s = src[i];
    int pos = row_ptr[d] + atomicAdd(&cursor[d], 1);
    float nrm = dinv[s] * dinv[d];
    csr_pk[pos] = (long long)(unsigned)s |
                  ((long long)__float_as_int(nrm) << 32);
  }
}

// x f32 -> f16
__global__ void k_x2f16(const float* __restrict__ x, u16* __restrict__ xh, int total4) {
  int i = blockIdx.x * blockDim.x + threadIdx.x;
  if (i >= total4) return;
  float4 v = ((const float4*)x)[i];
  ushort4 o;
  o.x = f2h(v.x); o.y = f2h(v.y); o.z = f2h(v.z); o.w = f2h(v.w);
  ((ushort4*)xh)[i] = o;
}

// W -> packed f16 hi/lo, scaled x256, t-slice-major fragment order:
// slice t (32 k): [hi: 16 ct x 64 lanes x 8 = 8192 u16][lo: 8192 u16]
// frag elem: lane L = q*16+m holds B[k=t*32+q*8+j][n=c*16+m] at (c*64+L)*8+j
__global__ void k_splitW3(const float* __restrict__ W1f, u16* __restrict__ P1,
                          const float* __restrict__ W2f, u16* __restrict__ P2,
                          const float* __restrict__ W3f, u16* __restrict__ P3) {
  int i = blockIdx.x * blockDim.x + threadIdx.x;
  const int s1 = DIN * 256, s2 = s1 + DHID * 256, s3 = s2 + DHID * 256;
  if (i >= s3) return;
  const float* W; u16* P; int li;
  if (i < s1)      { W = W1f; P = P1; li = i; }
  else if (i < s2) { W = W2f; P = P2; li = i - s1; }
  else             { W = W3f; P = P3; li = i - s2; }
  int k = li >> 8, n = li & 255;
  int t = k >> 5, q = (k >> 3) & 3, j = k & 7;
  int c = n >> 4, m = n & 15;
  int f = (c * 64 + q * 16 + m) * 8 + j;
  float w = W[li] * 256.0f;   // scale keeps lo residues f16-normal
  u16 hi = f2h(w);
  u16 lo = f2h(w - h2f(hi));
  P[(size_t)t * 16384 + f] = hi;
  P[(size_t)t * 16384 + 8192 + f] = lo;
}

// XCD-aligned column-panel aggregation.
// A[node] = dinv^2 * h[node] + sum_e w_e * h[src_e], done per 32-col panel.
// Panel = blockIdx % NPAN. With round-robin block->XCD dispatch, each XCD
// works ONE panel: gather working set = 50k * 64 B = 3.2 MB < 4 MB L2/XCD
// -> gathers become L2-resident; L2 misses drop to compulsory fill + CSR.
// Group = 4 lanes * 16 B = one edge's 64 B slice; 16 edges per wave instr.
// CSR is read once per panel via non-temporal loads (no L2 pollution).
template<int W>
__global__ __launch_bounds__(256) void k_aggP(const u16* __restrict__ hf,
                                              const float* __restrict__ dinv,
                                              const int* __restrict__ row_ptr,
                                              const long long* __restrict__ csr_pk,
                                              u16* __restrict__ aout, int n) {
  constexpr int NPAN = W / 32;                 // 8 (D=256) or 4 (D=128)
  constexpr int PSH = (NPAN == 8) ? 3 : 2;
  const int panel = blockIdx.x & (NPAN - 1);   // constant per XCD
  const int chunk = blockIdx.x >> PSH;
  const int nchunks = gridDim.x >> PSH;
  const int CH = (n + nchunks - 1) / nchunks;

  const int lane = threadIdx.x & 63;
  const int wave = threadIdx.x >> 6;
  const int g = lane >> 2;                     // 16 groups of 4 lanes
  const int sub = lane & 3;
  const int pc = panel * 32 + sub * 8;         // u16 col offset (16 B/lane)

  const int start = chunk * CH;
  int end = start + CH; if (end > n) end = n;

  for (int node = start + wave * 16 + g; node < end; node += 64) {
    float di = dinv[node];
    float s2 = di * di;
    float acc[8];
    {
      half8 v = *(const half8*)(hf + (size_t)node * W + pc);
#pragma unroll
      for (int j = 0; j < 8; ++j) acc[j] = s2 * (float)v[j];
    }
    const int p0 = row_ptr[node];
    const int p1 = row_ptr[node + 1];
    int e = p0;
    for (; e + 2 <= p1; e += 2) {
      long long c0 = __builtin_nontemporal_load(csr_pk + e);
      long long c1 = __builtin_nontemporal_load(csr_pk + e + 1);
      int s0 = (int)c0;  float w0 = __int_as_float((int)(c0 >> 32));
      int s1 = (int)c1;  float w1 = __int_as_float((int)(c1 >> 32));
      half8 v0 = *(const half8*)(hf + (size_t)s0 * W + pc);
      half8 v1 = *(const half8*)(hf + (size_t)s1 * W + pc);
#pragma unroll
      for (int j = 0; j < 8; ++j) {
        acc[j] = fmaf(w0, (float)v0[j], acc[j]);
        acc[j] = fmaf(w1, (float)v1[j], acc[j]);
      }
    }
    if (e < p1) {
      long long c0 = __builtin_nontemporal_load(csr_pk + e);
      int s0 = (int)c0;  float w0 = __int_as_float((int)(c0 >> 32));
      half8 v0 = *(const half8*)(hf + (size_t)s0 * W + pc);
#pragma unroll
      for (int j = 0; j < 8; ++j) acc[j] = fmaf(w0, (float)v0[j], acc[j]);
    }
    uint4 o;
    o.x = (unsigned)f2h(acc[0]) | ((unsigned)f2h(acc[1]) << 16);
    o.y = (unsigned)f2h(acc[2]) | ((unsigned)f2h(acc[3]) << 16);
    o.z = (unsigned)f2h(acc[4]) | ((unsigned)f2h(acc[5]) << 16);
    o.w = (unsigned)f2h(acc[6]) | ((unsigned)f2h(acc[7]) << 16);
    *(uint4*)(aout + (size_t)node * W + pc) = o;
  }
}

// C = A[M,K](f16) @ (Bhi+Blo)(f16, x256) / 256 + bias. 2-pass f16 MFMA.
// Block = 64 rows x 256 cols, 4 waves (2 row x 2 col), wave = 32r x 128c.
// B t-slice (32 KB) staged in LDS via global_load_lds, shared by all waves.
// EPI 0: relu + f16 store (all rows). EPI 1: f32 store, rows < NNODES.
template<int K, int EPI>
__global__ __launch_bounds__(256, 4) void k_gemm_mfma(const u16* __restrict__ A,
                                                      const u16* __restrict__ Bpk,
                                                      const float* __restrict__ bias,
                                                      u16* __restrict__ hf16,
                                                      float* __restrict__ outf) {
  __shared__ __align__(16) u16 Bs[16384];   // 32 KB: [hi 8192][lo 8192]
  const int lane = threadIdx.x & 63;
  const int wave = threadIdx.x >> 6;
  const int rw = wave & 1, cw = wave >> 1;
  const int m0 = blockIdx.x * 64 + rw * 32;

  f32x4 acc0[8], acc1[8];
#pragma unroll
  for (int c = 0; c < 8; ++c) {
    acc0[c] = {0.f, 0.f, 0.f, 0.f};
    acc1[c] = {0.f, 0.f, 0.f, 0.f};
  }

  const u16* a0p = A + (size_t)(m0 + (lane & 15)) * K + ((lane >> 4) * 8);
  const u16* a1p = a0p + (size_t)16 * K;

  for (int t = 0; t < K / 32; ++t) {
    __syncthreads();   // previous compute done before Bs overwrite
    {
      const char* gsrc = (const char*)(Bpk + (size_t)t * 16384);
      char* lbase = (char*)Bs;
#pragma unroll
      for (int it = 0; it < 8; ++it) {
        int off = (wave * 8 + it) * 1024 + lane * 16;
        GLDS16(gsrc + off, lbase + off);
      }
    }
    __syncthreads();   // drains vmcnt -> Bs valid

    half8 a0 = *(const half8*)(a0p + t * 32);
    half8 a1 = *(const half8*)(a1p + t * 32);
#pragma unroll
    for (int c = 0; c < 8; ++c) {
      const u16* fb = Bs + ((cw * 8 + c) * 64 + lane) * 8;
      half8 bh = *(const half8*)fb;
      half8 bl = *(const half8*)(fb + 8192);
      acc0[c] = __builtin_amdgcn_mfma_f32_16x16x32_f16(a0, bh, acc0[c], 0, 0, 0);
      acc0[c] = __builtin_amdgcn_mfma_f32_16x16x32_f16(a0, bl, acc0[c], 0, 0, 0);
      acc1[c] = __builtin_amdgcn_mfma_f32_16x16x32_f16(a1, bh, acc1[c], 0, 0, 0);
      acc1[c] = __builtin_amdgcn_mfma_f32_16x16x32_f16(a1, bl, acc1[c], 0, 0, 0);
    }
  }

  const int cbase = lane & 15;
  const int r0 = m0 + ((lane >> 4) * 4);
  const float sc = 1.0f / 256.0f;
#pragma unroll
  for (int c = 0; c < 8; ++c) {
    int col = (cw * 8 + c) * 16 + cbase;
    float bv = bias[col];
#pragma unroll
    for (int r = 0; r < 4; ++r) {
      float v0 = fmaf(acc0[c][r], sc, bv);
      float v1 = fmaf(acc1[c][r], sc, bv);
      if (EPI == 0) {
        v0 = fmaxf(v0, 0.f);
        v1 = fmaxf(v1, 0.f);
        hf16[(size_t)(r0 + r) * 256 + col] = f2h(v0);
        hf16[(size_t)(r0 + 16 + r) * 256 + col] = f2h(v1);
      } else {
        if (r0 + r < NNODES) outf[(size_t)(r0 + r) * 256 + col] = v0;
        if (r0 + 16 + r < NNODES) outf[(size_t)(r0 + 16 + r) * 256 + col] = v1;
      }
    }
  }
}

extern "C" void kernel_launch(void* const* d_in, const int* in_sizes, int n_in,
                              void* d_out, int out_size, void* d_ws, size_t ws_size,
                              hipStream_t stream) {
  const float* x  = (const float*)d_in[0];
  const int*   ei = (const int*)d_in[1];
  const float* W1 = (const float*)d_in[2];
  const float* b1 = (const float*)d_in[3];
  const float* W2 = (const float*)d_in[4];
  const float* b2 = (const float*)d_in[5];
  const float* W3 = (const float*)d_in[6];
  const float* b3 = (const float*)d_in[7];
  float* out = (float*)d_out;
  (void)in_sizes; (void)n_in; (void)out_size; (void)ws_size;

  char* ws = (char*)d_ws;
  size_t off = 0;
  auto alloc = [&](size_t bytes) -> void* {
    void* p = (void*)(ws + off);
    off += (bytes + 255) & ~(size_t)255;
    return p;
  };
  float* dinv    = (float*)alloc((size_t)NNODES * 4);
  int*   deg     = (int*)alloc((size_t)NNODES * 4);
  int*   row_ptr = (int*)alloc((size_t)(NNODES + 1) * 4);
  int*   partials= (int*)alloc((size_t)NSB * 4);
  long long* csr_pk = (long long*)alloc((size_t)NEDGES * 8);
  u16*   xh      = (u16*)alloc((size_t)NNODES * DIN * 2);    // x as f16
  u16*   hbuf    = (u16*)alloc((size_t)MPAD * 256 * 2);      // h f16 (gather src)
  u16*   A1      = (u16*)alloc((size_t)MPAD * DIN * 2);      // agg(x) f16
  u16*   A2      = (u16*)alloc((size_t)MPAD * 256 * 2);      // agg(h) f16
  u16*   W1pk    = (u16*)alloc((size_t)(DIN / 32) * 16384 * 2);
  u16*   W2pk    = (u16*)alloc((size_t)(DHID / 32) * 16384 * 2);
  u16*   W3pk    = (u16*)alloc((size_t)(DHID / 32) * 16384 * 2);

  const int* e_src = ei;
  const int* e_dst = ei + NEDGES;

  const int tb = 256;
  k_zero_i32<<<(NNODES + tb - 1) / tb, tb, 0, stream>>>(deg, NNODES);
  k_hist<<<(NEDGES + tb - 1) / tb, tb, 0, stream>>>(e_dst, deg, NEDGES);
  k_blocksum<<<NSB, 256, 0, stream>>>(deg, partials);
  k_scan2<<<NSB, 256, 0, stream>>>(deg, partials, row_ptr, dinv);
  k_fill<<<(NEDGES + tb - 1) / tb, tb, 0, stream>>>(e_src, e_dst, dinv, row_ptr, deg,
                                                    csr_pk, NEDGES);

  int x4 = NNODES * DIN / 4;
  k_x2f16<<<(x4 + tb - 1) / tb, tb, 0, stream>>>(x, xh, x4);
  int wtot = (DIN + DHID + DHID) * 256;
  k_splitW3<<<(wtot + tb - 1) / tb, tb, 0, stream>>>(W1, W1pk, W2, W2pk, W3, W3pk);

  const int gblocks = MPAD / 64;           // 782
  const int aggrid = 2048;                 // multiple of 8; 8 blocks/CU

  // layer 1
  k_aggP<128><<<aggrid, 256, 0, stream>>>(xh, dinv, row_ptr, csr_pk, A1, NNODES);
  k_gemm_mfma<DIN, 0><<<gblocks, 256, 0, stream>>>(A1, W1pk, b1, hbuf, nullptr);
  // layer 2
  k_aggP<256><<<aggrid, 256, 0, stream>>>(hbuf, dinv, row_ptr, csr_pk, A2, NNODES);
  k_gemm_mfma<DHID, 0><<<gblocks, 256, 0, stream>>>(A2, W2pk, b2, hbuf, nullptr);
  // layer 3
  k_aggP<256><<<aggrid, 256, 0, stream>>>(hbuf, dinv, row_ptr, csr_pk, A2, NNODES);
  k_gemm_mfma<DHID, 1><<<gblocks, 256, 0, stream>>>(A2, W3pk, b3, nullptr, out);
}

// Round 5
// 351.209 us; speedup vs baseline: 1.3193x; 1.3193x over previous
//
#include <hip/hip_runtime.h>

#define NNODES 50000
#define NEDGES 500000
#define DIN 128
#define DHID 256
#define MPAD 50048   // 782 blocks * 64 rows
#define NI4 12500
#define NSB 49

typedef unsigned short u16;
typedef __attribute__((ext_vector_type(8))) _Float16 half8;
typedef __attribute__((ext_vector_type(4))) float f32x4;

__device__ __forceinline__ u16 f2h(float f) {
  union { _Float16 h; u16 u; } v; v.h = (_Float16)f; return v.u;
}
__device__ __forceinline__ float h2f(unsigned int u) {
  union { _Float16 h; u16 u; } v; v.u = (u16)u; return (float)v.h;
}

#define GLDS16(g, l) __builtin_amdgcn_global_load_lds( \
    (const __attribute__((address_space(1))) void*)(g), \
    (__attribute__((address_space(3))) void*)(l), 16, 0, 0)

__global__ void k_zero_i32(int* __restrict__ p, int n) {
  int i = blockIdx.x * blockDim.x + threadIdx.x;
  if (i < n) p[i] = 0;
}

__global__ void k_hist(const int* __restrict__ dst, int* __restrict__ deg, int e) {
  int i = blockIdx.x * blockDim.x + threadIdx.x;
  if (i < e) atomicAdd(&deg[dst[i]], 1);
}

__global__ __launch_bounds__(256) void k_blocksum(const int* __restrict__ deg,
                                                  int* __restrict__ partials) {
  __shared__ int red[256];
  int tid = threadIdx.x;
  int t4 = blockIdx.x * 256 + tid;
  int sum = 0;
  if (t4 < NI4) {
    int4 v = ((const int4*)deg)[t4];
    sum = v.x + v.y + v.z + v.w;
  }
  red[tid] = sum;
  __syncthreads();
  for (int off = 128; off > 0; off >>= 1) {
    if (tid < off) red[tid] += red[tid + off];
    __syncthreads();
  }
  if (tid == 0) partials[blockIdx.x] = red[0];
}

// exclusive scan -> row_ptr; fused: dinv = rsqrt(deg+1), zero deg (cursor reuse)
__global__ __launch_bounds__(256) void k_scan2(int* __restrict__ deg,
                                               const int* __restrict__ partials,
                                               int* __restrict__ row_ptr,
                                               float* __restrict__ dinv) {
  __shared__ int sdata[256];
  __shared__ int sprefix;
  int tid = threadIdx.x, bid = blockIdx.x;
  int t4 = bid * 256 + tid;
  int4 v = make_int4(0, 0, 0, 0);
  if (t4 < NI4) v = ((const int4*)deg)[t4];
  int tsum = v.x + v.y + v.z + v.w;
  sdata[tid] = tsum;
  if (tid == 0) {
    int pre = 0;
    for (int b = 0; b < bid; ++b) pre += partials[b];
    sprefix = pre;
  }
  __syncthreads();
  for (int off = 1; off < 256; off <<= 1) {
    int val = (tid >= off) ? sdata[tid - off] : 0;
    __syncthreads();
    sdata[tid] += val;
    __syncthreads();
  }
  if (t4 < NI4) {
    int run = sdata[tid] - tsum + sprefix;
    int base = t4 * 4;
    float4 dv;
    dv.x = rsqrtf((float)v.x + 1.0f);
    dv.y = rsqrtf((float)v.y + 1.0f);
    dv.z = rsqrtf((float)v.z + 1.0f);
    dv.w = rsqrtf((float)v.w + 1.0f);
    *(float4*)(dinv + base) = dv;
    row_ptr[base + 0] = run; run += v.x;
    row_ptr[base + 1] = run; run += v.y;
    row_ptr[base + 2] = run; run += v.z;
    row_ptr[base + 3] = run; run += v.w;
    if (base + 4 == NNODES) row_ptr[NNODES] = run;
    ((int4*)deg)[t4] = make_int4(0, 0, 0, 0);
  }
}

__global__ void k_fill(const int* __restrict__ src, const int* __restrict__ dst,
                       const float* __restrict__ dinv, const int* __restrict__ row_ptr,
                       int* __restrict__ cursor, int* __restrict__ csr_src,
                       float* __restrict__ csr_nrm, int e) {
  int i = blockIdx.x * blockDim.x + threadIdx.x;
  if (i < e) {
    int d = dst[i], s = src[i];
    int pos = row_ptr[d] + atomicAdd(&cursor[d], 1);
    csr_src[pos] = s;
    csr_nrm[pos] = dinv[s] * dinv[d];
  }
}

// x f32 -> f16
__global__ void k_x2f16(const float* __restrict__ x, u16* __restrict__ xh, int total4) {
  int i = blockIdx.x * blockDim.x + threadIdx.x;
  if (i >= total4) return;
  float4 v = ((const float4*)x)[i];
  ushort4 o;
  o.x = f2h(v.x); o.y = f2h(v.y); o.z = f2h(v.z); o.w = f2h(v.w);
  ((ushort4*)xh)[i] = o;
}

// W -> packed f16 hi/lo, scaled x256, t-slice-major fragment order:
// slice t (32 k): [hi: 16 ct x 64 lanes x 8 = 8192 u16][lo: 8192 u16]
// frag elem: lane L = q*16+m holds B[k=t*32+q*8+j][n=c*16+m] at (c*64+L)*8+j
__global__ void k_splitW3(const float* __restrict__ W1f, u16* __restrict__ P1,
                          const float* __restrict__ W2f, u16* __restrict__ P2,
                          const float* __restrict__ W3f, u16* __restrict__ P3) {
  int i = blockIdx.x * blockDim.x + threadIdx.x;
  const int s1 = DIN * 256, s2 = s1 + DHID * 256, s3 = s2 + DHID * 256;
  if (i >= s3) return;
  const float* W; u16* P; int li;
  if (i < s1)      { W = W1f; P = P1; li = i; }
  else if (i < s2) { W = W2f; P = P2; li = i - s1; }
  else             { W = W3f; P = P3; li = i - s2; }
  int k = li >> 8, n = li & 255;
  int t = k >> 5, q = (k >> 3) & 3, j = k & 7;
  int c = n >> 4, m = n & 15;
  int f = (c * 64 + q * 16 + m) * 8 + j;
  float w = W[li] * 256.0f;   // scale keeps lo residues f16-normal
  u16 hi = f2h(w);
  u16 lo = f2h(w - h2f(hi));
  P[(size_t)t * 16384 + f] = hi;
  P[(size_t)t * 16384 + 8192 + f] = lo;
}

// Fused layer: phase A aggregates this block's 64 rows into a swizzled LDS
// A-tile (A[node] = dinv^2*h[node] + sum_e w_e*h[src_e], f16), phase B runs
// the 2-pass hi/lo MFMA GEMM reading A from LDS. Cross-block co-scheduling
// (2 blocks/CU) overlaps gather-miss latency with MFMA/staging stalls.
// Swizzle: u16col ^= (row&7)<<3 -> conflict-free ds_read_b128 both sides.
// EPI 0: relu + f16 store (all rows). EPI 1: f32 store, rows < NNODES.
template<int K, int EPI>
__global__ __launch_bounds__(256, 2) void k_fused(const u16* __restrict__ hf,
                                                  const float* __restrict__ dinv,
                                                  const int* __restrict__ row_ptr,
                                                  const int* __restrict__ csr_src,
                                                  const float* __restrict__ csr_nrm,
                                                  const u16* __restrict__ Bpk,
                                                  const float* __restrict__ bias,
                                                  u16* __restrict__ hf16,
                                                  float* __restrict__ outf) {
  __shared__ __align__(16) u16 As[64 * K];  // 16 KB (K=128) / 32 KB (K=256)
  __shared__ __align__(16) u16 Bs[16384];   // 32 KB: [hi 8192][lo 8192]

  // ---------------- phase A: aggregate 64 rows into As ----------------
  {
    constexpr int GL = K / 8;       // lanes per row-group (full row, 16 B/lane)
    constexpr int NGRP = 256 / GL;  // row groups per block
    constexpr int RPG = 64 / NGRP;  // rows per group
    const int gg = threadIdx.x / GL;
    const int sub = threadIdx.x % GL;
    const int coff = sub * 8;       // u16 col
    const int nbase = blockIdx.x * 64;

    for (int k = 0; k < RPG; ++k) {
      const int row = gg + k * NGRP;
      const int node = nbase + row;
      float acc[8];
      if (node < NNODES) {
        float di = dinv[node];
        float s2 = di * di;
        {
          half8 v = *(const half8*)(hf + (size_t)node * K + coff);
#pragma unroll
          for (int j = 0; j < 8; ++j) acc[j] = s2 * (float)v[j];
        }
        const int p0 = row_ptr[node];
        const int p1 = row_ptr[node + 1];
        for (int e = p0; e < p1; e += 8) {
          int idx[8]; float w[8];
#pragma unroll
          for (int q = 0; q < 8; ++q) {
            int ii = (e + q < p1) ? e + q : p1 - 1;
            idx[q] = csr_src[ii];
            w[q] = (e + q < p1) ? csr_nrm[ii] : 0.0f;
          }
          half8 v[8];
#pragma unroll
          for (int q = 0; q < 8; ++q)
            v[q] = *(const half8*)(hf + (size_t)idx[q] * K + coff);
#pragma unroll
          for (int q = 0; q < 8; ++q)
#pragma unroll
            for (int j = 0; j < 8; ++j)
              acc[j] = fmaf(w[q], (float)v[q][j], acc[j]);
        }
      } else {
#pragma unroll
        for (int j = 0; j < 8; ++j) acc[j] = 0.0f;
      }
      const int wc = coff ^ ((row & 7) << 3);
      uint4 o;
      o.x = (unsigned)f2h(acc[0]) | ((unsigned)f2h(acc[1]) << 16);
      o.y = (unsigned)f2h(acc[2]) | ((unsigned)f2h(acc[3]) << 16);
      o.z = (unsigned)f2h(acc[4]) | ((unsigned)f2h(acc[5]) << 16);
      o.w = (unsigned)f2h(acc[6]) | ((unsigned)f2h(acc[7]) << 16);
      *(uint4*)&As[row * K + wc] = o;
    }
  }

  // ---------------- phase B: GEMM from LDS A-tile ----------------
  const int lane = threadIdx.x & 63;
  const int wave = threadIdx.x >> 6;
  const int rw = wave & 1, cw = wave >> 1;
  const int m0 = blockIdx.x * 64 + rw * 32;
  const int lr0 = rw * 32 + (lane & 15);
  const int lr1 = lr0 + 16;
  const int acoff = (lane >> 4) * 8;

  f32x4 acc0[8], acc1[8];
#pragma unroll
  for (int c = 0; c < 8; ++c) {
    acc0[c] = {0.f, 0.f, 0.f, 0.f};
    acc1[c] = {0.f, 0.f, 0.f, 0.f};
  }

  for (int t = 0; t < K / 32; ++t) {
    __syncthreads();   // t=0: As complete; t>0: previous compute done
    {
      const char* gsrc = (const char*)(Bpk + (size_t)t * 16384);
      char* lbase = (char*)Bs;
#pragma unroll
      for (int it = 0; it < 8; ++it) {
        int off = (wave * 8 + it) * 1024 + lane * 16;
        GLDS16(gsrc + off, lbase + off);
      }
    }
    __syncthreads();   // drains vmcnt -> Bs valid

    const int ac = acoff + t * 32;
    half8 a0 = *(const half8*)&As[lr0 * K + (ac ^ ((lr0 & 7) << 3))];
    half8 a1 = *(const half8*)&As[lr1 * K + (ac ^ ((lr1 & 7) << 3))];
#pragma unroll
    for (int c = 0; c < 8; ++c) {
      const u16* fb = Bs + ((cw * 8 + c) * 64 + lane) * 8;
      half8 bh = *(const half8*)fb;
      half8 bl = *(const half8*)(fb + 8192);
      acc0[c] = __builtin_amdgcn_mfma_f32_16x16x32_f16(a0, bh, acc0[c], 0, 0, 0);
      acc0[c] = __builtin_amdgcn_mfma_f32_16x16x32_f16(a0, bl, acc0[c], 0, 0, 0);
      acc1[c] = __builtin_amdgcn_mfma_f32_16x16x32_f16(a1, bh, acc1[c], 0, 0, 0);
      acc1[c] = __builtin_amdgcn_mfma_f32_16x16x32_f16(a1, bl, acc1[c], 0, 0, 0);
    }
  }

  const int cbase = lane & 15;
  const int r0 = m0 + ((lane >> 4) * 4);
  const float sc = 1.0f / 256.0f;
#pragma unroll
  for (int c = 0; c < 8; ++c) {
    int col = (cw * 8 + c) * 16 + cbase;
    float bv = bias[col];
#pragma unroll
    for (int r = 0; r < 4; ++r) {
      float v0 = fmaf(acc0[c][r], sc, bv);
      float v1 = fmaf(acc1[c][r], sc, bv);
      if (EPI == 0) {
        v0 = fmaxf(v0, 0.f);
        v1 = fmaxf(v1, 0.f);
        hf16[(size_t)(r0 + r) * 256 + col] = f2h(v0);
        hf16[(size_t)(r0 + 16 + r) * 256 + col] = f2h(v1);
      } else {
        if (r0 + r < NNODES) outf[(size_t)(r0 + r) * 256 + col] = v0;
        if (r0 + 16 + r < NNODES) outf[(size_t)(r0 + 16 + r) * 256 + col] = v1;
      }
    }
  }
}

extern "C" void kernel_launch(void* const* d_in, const int* in_sizes, int n_in,
                              void* d_out, int out_size, void* d_ws, size_t ws_size,
                              hipStream_t stream) {
  const float* x  = (const float*)d_in[0];
  const int*   ei = (const int*)d_in[1];
  const float* W1 = (const float*)d_in[2];
  const float* b1 = (const float*)d_in[3];
  const float* W2 = (const float*)d_in[4];
  const float* b2 = (const float*)d_in[5];
  const float* W3 = (const float*)d_in[6];
  const float* b3 = (const float*)d_in[7];
  float* out = (float*)d_out;
  (void)in_sizes; (void)n_in; (void)out_size; (void)ws_size;

  char* ws = (char*)d_ws;
  size_t off = 0;
  auto alloc = [&](size_t bytes) -> void* {
    void* p = (void*)(ws + off);
    off += (bytes + 255) & ~(size_t)255;
    return p;
  };
  float* dinv    = (float*)alloc((size_t)NNODES * 4);
  int*   deg     = (int*)alloc((size_t)NNODES * 4);
  int*   row_ptr = (int*)alloc((size_t)(NNODES + 1) * 4);
  int*   partials= (int*)alloc((size_t)NSB * 4);
  int*   csr_src = (int*)alloc((size_t)NEDGES * 4);
  float* csr_nrm = (float*)alloc((size_t)NEDGES * 4);
  u16*   xh      = (u16*)alloc((size_t)NNODES * DIN * 2);    // x as f16
  u16*   hbufA   = (u16*)alloc((size_t)MPAD * 256 * 2);      // h1 f16
  u16*   hbufB   = (u16*)alloc((size_t)MPAD * 256 * 2);      // h2 f16
  u16*   W1pk    = (u16*)alloc((size_t)(DIN / 32) * 16384 * 2);
  u16*   W2pk    = (u16*)alloc((size_t)(DHID / 32) * 16384 * 2);
  u16*   W3pk    = (u16*)alloc((size_t)(DHID / 32) * 16384 * 2);

  const int* e_src = ei;
  const int* e_dst = ei + NEDGES;

  const int tb = 256;
  k_zero_i32<<<(NNODES + tb - 1) / tb, tb, 0, stream>>>(deg, NNODES);
  k_hist<<<(NEDGES + tb - 1) / tb, tb, 0, stream>>>(e_dst, deg, NEDGES);
  k_blocksum<<<NSB, 256, 0, stream>>>(deg, partials);
  k_scan2<<<NSB, 256, 0, stream>>>(deg, partials, row_ptr, dinv);
  k_fill<<<(NEDGES + tb - 1) / tb, tb, 0, stream>>>(e_src, e_dst, dinv, row_ptr, deg,
                                                    csr_src, csr_nrm, NEDGES);

  int x4 = NNODES * DIN / 4;
  k_x2f16<<<(x4 + tb - 1) / tb, tb, 0, stream>>>(x, xh, x4);
  int wtot = (DIN + DHID + DHID) * 256;
  k_splitW3<<<(wtot + tb - 1) / tb, tb, 0, stream>>>(W1, W1pk, W2, W2pk, W3, W3pk);

  const int gblocks = MPAD / 64;           // 782

  // layer 1: agg(x)@W1 fused
  k_fused<DIN, 0><<<gblocks, 256, 0, stream>>>(xh, dinv, row_ptr, csr_src, csr_nrm,
                                               W1pk, b1, hbufA, nullptr);
  // layer 2
  k_fused<DHID, 0><<<gblocks, 256, 0, stream>>>(hbufA, dinv, row_ptr, csr_src, csr_nrm,
                                                W2pk, b2, hbufB, nullptr);
  // layer 3
  k_fused<DHID, 1><<<gblocks, 256, 0, stream>>>(hbufB, dinv, row_ptr, csr_src, csr_nrm,
                                                W3pk, b3, nullptr, out);
}

// Round 6
// 327.665 us; speedup vs baseline: 1.4141x; 1.0719x over previous
//
#include <hip/hip_runtime.h>

#define NNODES 50000
#define NEDGES 500000
#define DIN 128
#define DHID 256
#define MPAD 50048   // 782 blocks * 64 rows
#define NI4 12500
#define NSB 49

typedef unsigned short u16;
typedef __attribute__((ext_vector_type(8))) _Float16 half8;
typedef __attribute__((ext_vector_type(4))) float f32x4;

__device__ __forceinline__ u16 f2h(float f) {
  union { _Float16 h; u16 u; } v; v.h = (_Float16)f; return v.u;
}
__device__ __forceinline__ float h2f(unsigned int u) {
  union { _Float16 h; u16 u; } v; v.u = (u16)u; return (float)v.h;
}

__global__ void k_zero_i32(int* __restrict__ p, int n) {
  int i = blockIdx.x * blockDim.x + threadIdx.x;
  if (i < n) p[i] = 0;
}

__global__ void k_hist(const int* __restrict__ dst, int* __restrict__ deg, int e) {
  int i = blockIdx.x * blockDim.x + threadIdx.x;
  if (i < e) atomicAdd(&deg[dst[i]], 1);
}

__global__ __launch_bounds__(256) void k_blocksum(const int* __restrict__ deg,
                                                  int* __restrict__ partials) {
  __shared__ int red[256];
  int tid = threadIdx.x;
  int t4 = blockIdx.x * 256 + tid;
  int sum = 0;
  if (t4 < NI4) {
    int4 v = ((const int4*)deg)[t4];
    sum = v.x + v.y + v.z + v.w;
  }
  red[tid] = sum;
  __syncthreads();
  for (int off = 128; off > 0; off >>= 1) {
    if (tid < off) red[tid] += red[tid + off];
    __syncthreads();
  }
  if (tid == 0) partials[blockIdx.x] = red[0];
}

// exclusive scan -> row_ptr; fused: dinv = rsqrt(deg+1), zero deg (cursor reuse)
__global__ __launch_bounds__(256) void k_scan2(int* __restrict__ deg,
                                               const int* __restrict__ partials,
                                               int* __restrict__ row_ptr,
                                               float* __restrict__ dinv) {
  __shared__ int sdata[256];
  __shared__ int sprefix;
  int tid = threadIdx.x, bid = blockIdx.x;
  int t4 = bid * 256 + tid;
  int4 v = make_int4(0, 0, 0, 0);
  if (t4 < NI4) v = ((const int4*)deg)[t4];
  int tsum = v.x + v.y + v.z + v.w;
  sdata[tid] = tsum;
  if (tid == 0) {
    int pre = 0;
    for (int b = 0; b < bid; ++b) pre += partials[b];
    sprefix = pre;
  }
  __syncthreads();
  for (int off = 1; off < 256; off <<= 1) {
    int val = (tid >= off) ? sdata[tid - off] : 0;
    __syncthreads();
    sdata[tid] += val;
    __syncthreads();
  }
  if (t4 < NI4) {
    int run = sdata[tid] - tsum + sprefix;
    int base = t4 * 4;
    float4 dv;
    dv.x = rsqrtf((float)v.x + 1.0f);
    dv.y = rsqrtf((float)v.y + 1.0f);
    dv.z = rsqrtf((float)v.z + 1.0f);
    dv.w = rsqrtf((float)v.w + 1.0f);
    *(float4*)(dinv + base) = dv;
    row_ptr[base + 0] = run; run += v.x;
    row_ptr[base + 1] = run; run += v.y;
    row_ptr[base + 2] = run; run += v.z;
    row_ptr[base + 3] = run; run += v.w;
    if (base + 4 == NNODES) row_ptr[NNODES] = run;
    ((int4*)deg)[t4] = make_int4(0, 0, 0, 0);
  }
}

__global__ void k_fill(const int* __restrict__ src, const int* __restrict__ dst,
                       const float* __restrict__ dinv, const int* __restrict__ row_ptr,
                       int* __restrict__ cursor, int* __restrict__ csr_src,
                       float* __restrict__ csr_nrm, int e) {
  int i = blockIdx.x * blockDim.x + threadIdx.x;
  if (i < e) {
    int d = dst[i], s = src[i];
    int pos = row_ptr[d] + atomicAdd(&cursor[d], 1);
    csr_src[pos] = s;
    csr_nrm[pos] = dinv[s] * dinv[d];
  }
}

// Merged prep: x f32->f16 (ranges [0, x4)) + W hi/lo split ([0, wtot)).
// W packed f16 hi/lo, scaled x256, t-slice-major fragment order:
// slice t (32 k): [hi: 16 ct x 64 lanes x 8 = 8192 u16][lo: 8192 u16]
// frag elem: lane L = q*16+m holds B[k=t*32+q*8+j][n=c*16+m] at (c*64+L)*8+j
__global__ void k_prep(const float* __restrict__ x, u16* __restrict__ xh, int total4,
                       const float* __restrict__ W1f, u16* __restrict__ P1,
                       const float* __restrict__ W2f, u16* __restrict__ P2,
                       const float* __restrict__ W3f, u16* __restrict__ P3) {
  int i = blockIdx.x * blockDim.x + threadIdx.x;
  if (i < total4) {
    float4 v = ((const float4*)x)[i];
    ushort4 o;
    o.x = f2h(v.x); o.y = f2h(v.y); o.z = f2h(v.z); o.w = f2h(v.w);
    ((ushort4*)xh)[i] = o;
  }
  const int s1 = DIN * 256, s2 = s1 + DHID * 256, s3 = s2 + DHID * 256;
  if (i < s3) {
    const float* W; u16* P; int li;
    if (i < s1)      { W = W1f; P = P1; li = i; }
    else if (i < s2) { W = W2f; P = P2; li = i - s1; }
    else             { W = W3f; P = P3; li = i - s2; }
    int k = li >> 8, n = li & 255;
    int t = k >> 5, q = (k >> 3) & 3, j = k & 7;
    int c = n >> 4, m = n & 15;
    int f = (c * 64 + q * 16 + m) * 8 + j;
    float w = W[li] * 256.0f;   // scale keeps lo residues f16-normal
    u16 hi = f2h(w);
    u16 lo = f2h(w - h2f(hi));
    P[(size_t)t * 16384 + f] = hi;
    P[(size_t)t * 16384 + 8192 + f] = lo;
  }
}

// Fused layer v2: phase A aggregates this block's 64 rows into a swizzled
// LDS A-tile; phase B is a barrier-free MFMA GEMM reading A from LDS and B
// fragments DIRECTLY from global (fragment-ordered, L2-resident, coalesced
// 16 B/lane). LDS = As only -> 4 blocks/CU resident, so the gather phase
// keeps ~16 waves/CU and cross-block co-scheduling overlaps gather misses
// with other blocks' MFMA.
// Swizzle: u16col ^= (row&7)<<3 -> conflict-free ds_read_b128 both sides.
// EPI 0: relu + f16 store (all rows). EPI 1: f32 store, rows < NNODES.
template<int K, int EPI>
__global__ __launch_bounds__(256, 4) void k_fused(const u16* __restrict__ hf,
                                                  const float* __restrict__ dinv,
                                                  const int* __restrict__ row_ptr,
                                                  const int* __restrict__ csr_src,
                                                  const float* __restrict__ csr_nrm,
                                                  const u16* __restrict__ Bpk,
                                                  const float* __restrict__ bias,
                                                  u16* __restrict__ hf16,
                                                  float* __restrict__ outf) {
  __shared__ __align__(16) u16 As[64 * K];  // 16 KB (K=128) / 32 KB (K=256)

  // ---------------- phase A: aggregate 64 rows into As ----------------
  {
    constexpr int GL = K / 8;       // lanes per row-group (full row, 16 B/lane)
    constexpr int NGRP = 256 / GL;  // row groups per block
    constexpr int RPG = 64 / NGRP;  // rows per group
    const int gg = threadIdx.x / GL;
    const int sub = threadIdx.x % GL;
    const int coff = sub * 8;       // u16 col
    const int nbase = blockIdx.x * 64;

    for (int k = 0; k < RPG; ++k) {
      const int row = gg + k * NGRP;
      const int node = nbase + row;
      float acc[8];
      if (node < NNODES) {
        float di = dinv[node];
        float s2 = di * di;
        {
          half8 v = *(const half8*)(hf + (size_t)node * K + coff);
#pragma unroll
          for (int j = 0; j < 8; ++j) acc[j] = s2 * (float)v[j];
        }
        const int p0 = row_ptr[node];
        const int p1 = row_ptr[node + 1];
        for (int e = p0; e < p1; e += 8) {
          int idx[8]; float w[8];
#pragma unroll
          for (int q = 0; q < 8; ++q) {
            int ii = (e + q < p1) ? e + q : p1 - 1;
            idx[q] = csr_src[ii];
            w[q] = (e + q < p1) ? csr_nrm[ii] : 0.0f;
          }
          half8 v[8];
#pragma unroll
          for (int q = 0; q < 8; ++q)
            v[q] = *(const half8*)(hf + (size_t)idx[q] * K + coff);
#pragma unroll
          for (int q = 0; q < 8; ++q)
#pragma unroll
            for (int j = 0; j < 8; ++j)
              acc[j] = fmaf(w[q], (float)v[q][j], acc[j]);
        }
      } else {
#pragma unroll
        for (int j = 0; j < 8; ++j) acc[j] = 0.0f;
      }
      const int wc = coff ^ ((row & 7) << 3);
      uint4 o;
      o.x = (unsigned)f2h(acc[0]) | ((unsigned)f2h(acc[1]) << 16);
      o.y = (unsigned)f2h(acc[2]) | ((unsigned)f2h(acc[3]) << 16);
      o.z = (unsigned)f2h(acc[4]) | ((unsigned)f2h(acc[5]) << 16);
      o.w = (unsigned)f2h(acc[6]) | ((unsigned)f2h(acc[7]) << 16);
      *(uint4*)&As[row * K + wc] = o;
    }
  }

  __syncthreads();   // As complete; no further barriers needed

  // ------- phase B: barrier-free GEMM, A from LDS, B from global -------
  const int lane = threadIdx.x & 63;
  const int wave = threadIdx.x >> 6;
  const int rw = wave & 1, cw = wave >> 1;
  const int m0 = blockIdx.x * 64 + rw * 32;
  const int lr0 = rw * 32 + (lane & 15);
  const int lr1 = lr0 + 16;
  const int acoff = (lane >> 4) * 8;

  f32x4 acc0[8], acc1[8];
#pragma unroll
  for (int c = 0; c < 8; ++c) {
    acc0[c] = {0.f, 0.f, 0.f, 0.f};
    acc1[c] = {0.f, 0.f, 0.f, 0.f};
  }

  for (int t = 0; t < K / 32; ++t) {
    const int ac = acoff + t * 32;
    half8 a0 = *(const half8*)&As[lr0 * K + (ac ^ ((lr0 & 7) << 3))];
    half8 a1 = *(const half8*)&As[lr1 * K + (ac ^ ((lr1 & 7) << 3))];
    const u16* bt = Bpk + (size_t)t * 16384 + ((size_t)cw * 8 * 64 + lane) * 8;
#pragma unroll
    for (int c = 0; c < 8; ++c) {
      const u16* fb = bt + c * 512;
      half8 bh = *(const half8*)fb;
      half8 bl = *(const half8*)(fb + 8192);
      acc0[c] = __builtin_amdgcn_mfma_f32_16x16x32_f16(a0, bh, acc0[c], 0, 0, 0);
      acc0[c] = __builtin_amdgcn_mfma_f32_16x16x32_f16(a0, bl, acc0[c], 0, 0, 0);
      acc1[c] = __builtin_amdgcn_mfma_f32_16x16x32_f16(a1, bh, acc1[c], 0, 0, 0);
      acc1[c] = __builtin_amdgcn_mfma_f32_16x16x32_f16(a1, bl, acc1[c], 0, 0, 0);
    }
  }

  const int cbase = lane & 15;
  const int r0 = m0 + ((lane >> 4) * 4);
  const float sc = 1.0f / 256.0f;
#pragma unroll
  for (int c = 0; c < 8; ++c) {
    int col = (cw * 8 + c) * 16 + cbase;
    float bv = bias[col];
#pragma unroll
    for (int r = 0; r < 4; ++r) {
      float v0 = fmaf(acc0[c][r], sc, bv);
      float v1 = fmaf(acc1[c][r], sc, bv);
      if (EPI == 0) {
        v0 = fmaxf(v0, 0.f);
        v1 = fmaxf(v1, 0.f);
        hf16[(size_t)(r0 + r) * 256 + col] = f2h(v0);
        hf16[(size_t)(r0 + 16 + r) * 256 + col] = f2h(v1);
      } else {
        if (r0 + r < NNODES) outf[(size_t)(r0 + r) * 256 + col] = v0;
        if (r0 + 16 + r < NNODES) outf[(size_t)(r0 + 16 + r) * 256 + col] = v1;
      }
    }
  }
}

extern "C" void kernel_launch(void* const* d_in, const int* in_sizes, int n_in,
                              void* d_out, int out_size, void* d_ws, size_t ws_size,
                              hipStream_t stream) {
  const float* x  = (const float*)d_in[0];
  const int*   ei = (const int*)d_in[1];
  const float* W1 = (const float*)d_in[2];
  const float* b1 = (const float*)d_in[3];
  const float* W2 = (const float*)d_in[4];
  const float* b2 = (const float*)d_in[5];
  const float* W3 = (const float*)d_in[6];
  const float* b3 = (const float*)d_in[7];
  float* out = (float*)d_out;
  (void)in_sizes; (void)n_in; (void)out_size; (void)ws_size;

  char* ws = (char*)d_ws;
  size_t off = 0;
  auto alloc = [&](size_t bytes) -> void* {
    void* p = (void*)(ws + off);
    off += (bytes + 255) & ~(size_t)255;
    return p;
  };
  float* dinv    = (float*)alloc((size_t)NNODES * 4);
  int*   deg     = (int*)alloc((size_t)NNODES * 4);
  int*   row_ptr = (int*)alloc((size_t)(NNODES + 1) * 4);
  int*   partials= (int*)alloc((size_t)NSB * 4);
  int*   csr_src = (int*)alloc((size_t)NEDGES * 4);
  float* csr_nrm = (float*)alloc((size_t)NEDGES * 4);
  u16*   xh      = (u16*)alloc((size_t)NNODES * DIN * 2);    // x as f16
  u16*   hbufA   = (u16*)alloc((size_t)MPAD * 256 * 2);      // h1 f16
  u16*   hbufB   = (u16*)alloc((size_t)MPAD * 256 * 2);      // h2 f16
  u16*   W1pk    = (u16*)alloc((size_t)(DIN / 32) * 16384 * 2);
  u16*   W2pk    = (u16*)alloc((size_t)(DHID / 32) * 16384 * 2);
  u16*   W3pk    = (u16*)alloc((size_t)(DHID / 32) * 16384 * 2);

  const int* e_src = ei;
  const int* e_dst = ei + NEDGES;

  const int tb = 256;
  k_zero_i32<<<(NNODES + tb - 1) / tb, tb, 0, stream>>>(deg, NNODES);
  k_hist<<<(NEDGES + tb - 1) / tb, tb, 0, stream>>>(e_dst, deg, NEDGES);
  k_blocksum<<<NSB, 256, 0, stream>>>(deg, partials);
  k_scan2<<<NSB, 256, 0, stream>>>(deg, partials, row_ptr, dinv);
  k_fill<<<(NEDGES + tb - 1) / tb, tb, 0, stream>>>(e_src, e_dst, dinv, row_ptr, deg,
                                                    csr_src, csr_nrm, NEDGES);

  int x4 = NNODES * DIN / 4;
  k_prep<<<(x4 + tb - 1) / tb, tb, 0, stream>>>(x, xh, x4,
                                                W1, W1pk, W2, W2pk, W3, W3pk);

  const int gblocks = MPAD / 64;           // 782

  // layer 1: agg(x)@W1 fused
  k_fused<DIN, 0><<<gblocks, 256, 0, stream>>>(xh, dinv, row_ptr, csr_src, csr_nrm,
                                               W1pk, b1, hbufA, nullptr);
  // layer 2
  k_fused<DHID, 0><<<gblocks, 256, 0, stream>>>(hbufA, dinv, row_ptr, csr_src, csr_nrm,
                                                W2pk, b2, hbufB, nullptr);
  // layer 3
  k_fused<DHID, 1><<<gblocks, 256, 0, stream>>>(hbufB, dinv, row_ptr, csr_src, csr_nrm,
                                                W3pk, b3, nullptr, out);
}